// Round 1
// 941.071 us; speedup vs baseline: 1.1493x; 1.1493x over previous
//
#include <hip/hip_runtime.h>
#include <hip/hip_bf16.h>
#include <cstddef>
#include <cstdint>

#define NN 2048      // nodes (M and K of the big GEMMs)
#define CIN 2
#define HH 32        // hidden
#define EMB 16
#define HOR 12
#define BB 32        // batch
#define TT 16        // time steps
#define GC 128       // 4*HH gate channels
#define XCOLS 1024   // B*T*C
#define HCOLS 1024   // B*H  (GEMM N dim)
#define KSPLIT 4
#define KS (NN / KSPLIT)          // 512 per k-slice
#define NIT (KS / 32)             // 16 K-tiles (BK=32) per slice
#define CSZ ((size_t)NN * HCOLS)  // one partial C: 2M floats

// Tiled fp16 operand layouts (32-k tiles, 8-elem chunks), matching the GEMM's
// LDS layout exactly so staging is a LINEAR contiguous copy:
//   A2t [tt=64][ko=4][row=2048][e=8] : elem ((tt*4+ko)*2048+row)*8+e = A[row][tt*32+ko*8+e]
//   hTt [tt=64][ko=4][col=1024][e=8] : elem ((tt*4+ko)*1024+col)*8+e = h[node=tt*32+ko*8+e][col]
//   B2xt: hi plane same shape as hTt; lo plane at +LOPLANE elements.
#define ATILE_STRIDE 65536   // 4*2048*8 elements per 32-k tile of A
#define BTILE_STRIDE 32768   // 4*1024*8 elements per 32-k tile of B
#define LOPLANE 2097152      // elements per x plane (64*4*1024*8)

typedef __attribute__((ext_vector_type(8))) _Float16 f16x8;
typedef __attribute__((ext_vector_type(16))) float f32x16;
typedef unsigned short u16;

// ---------------------------------------------------------------------------
// Kernel 1: A = softmax(relu(E1 @ E2^T)) -> A2t tiled fp16
// ---------------------------------------------------------------------------
__global__ __launch_bounds__(256) void adj_softmax(const float* __restrict__ E1,
                                                   const float* __restrict__ E2,
                                                   _Float16* __restrict__ A2) {
    const int i = blockIdx.x;
    __shared__ float red[256];
    float e1[EMB];
#pragma unroll
    for (int k = 0; k < EMB; ++k) e1[k] = E1[i * EMB + k];

    float s[8];
    float mx = -1e30f;
#pragma unroll
    for (int q = 0; q < 8; ++q) {
        const int j = q * 256 + threadIdx.x;
        float d = 0.f;
#pragma unroll
        for (int k = 0; k < EMB; ++k) d += e1[k] * E2[j * EMB + k];
        d = fmaxf(d, 0.0f);
        s[q] = d;
        mx = fmaxf(mx, d);
    }
    red[threadIdx.x] = mx;
    __syncthreads();
    for (int off = 128; off > 0; off >>= 1) {
        if (threadIdx.x < off) red[threadIdx.x] = fmaxf(red[threadIdx.x], red[threadIdx.x + off]);
        __syncthreads();
    }
    mx = red[0];
    __syncthreads();

    float sum = 0.f;
#pragma unroll
    for (int q = 0; q < 8; ++q) { s[q] = expf(s[q] - mx); sum += s[q]; }
    red[threadIdx.x] = sum;
    __syncthreads();
    for (int off = 128; off > 0; off >>= 1) {
        if (threadIdx.x < off) red[threadIdx.x] += red[threadIdx.x + off];
        __syncthreads();
    }
    const float inv = 1.0f / red[0];
#pragma unroll
    for (int q = 0; q < 8; ++q) {
        const int j  = q * 256 + threadIdx.x;      // k-index of A row i
        const int tt = j >> 5, ko = (j >> 3) & 3, e = j & 7;
        A2[((size_t)(tt * 4 + ko) * 2048 + i) * 8 + e] = (_Float16)(s[q] * inv);
    }
}

// ---------------------------------------------------------------------------
// Kernel 2: x -> B2xt tiled hi/lo fp16 planes (col = (b*T+t)*C + c).
// ---------------------------------------------------------------------------
__global__ __launch_bounds__(256) void transpose_x(const float* __restrict__ x,
                                                   _Float16* __restrict__ B2x) {
    const int idx = blockIdx.x * 256 + threadIdx.x;
    const int col = idx >> 11;
    const int j   = idx & (NN - 1);               // node index (gemm K dim)
    const int bt  = col >> 1;
    const int c   = col & 1;
    const float v = x[((size_t)bt * NN + j) * CIN + c];
    const _Float16 hi = (_Float16)v;
    const _Float16 lo = (_Float16)(v - (float)hi);
    const int tt = j >> 5, ko = (j >> 3) & 3, e = j & 7;
    const size_t base = ((size_t)(tt * 4 + ko) * 1024 + col) * 8 + e;
    B2x[base] = hi; B2x[base + LOPLANE] = lo;
}

// ---------------------------------------------------------------------------
// Kernel 3: fp16 MFMA GEMM (32x32x16), pipelined LDS double-buffer.
// Cp[z][2048][1024] = A[.][z-slice] * B[z-slice][.]
// NPROD=1: C = A*B (hTt)                 - recurrent path.
// NPROD=2: C = A*Bhi + A*Blo (B2xt)      - x path.
// Block 128x128, 4 waves each 64x64 (2x2 accs of 32x32), BK=32, KSPLIT=4.
// Flat 512-block grid with XCD swizzle: xcd=wg&7 owns 4 n-blocks x 1 k-slice
// x all 16 m-blocks -> per-XCD set = 2MB A-slice + 0.5MB h (fits 4MB L2).
// Staging: operands pre-tiled to the LDS layout -> wave loads are 1KB
// contiguous (16 lines vs 64 scattered before); LDS writes linear cid*16.
// ---------------------------------------------------------------------------
template <int NPROD>
__global__ __launch_bounds__(256, 2) void gemm_f16(const _Float16* __restrict__ A2,
                                                   const _Float16* __restrict__ B2,
                                                   float* __restrict__ Cp) {
    constexpr int BUF  = 8192 + NPROD * 8192;     // bytes per LDS buffer
    __shared__ char smem[2 * BUF];
    const int tid  = threadIdx.x;
    const int w    = tid >> 6;
    const int lane = tid & 63;

    // XCD-aware decomposition of (nb 8) x (mb 16) x (zz 4)
    const int wg  = blockIdx.x;
    const int xcd = wg & 7;
    const int wi  = wg >> 3;                      // 0..63 slot within XCD
    const int nb  = (xcd & 1) * 4 + (wi & 3);
    const int zz  = xcd >> 1;
    const int mb  = wi >> 2;
    const int m0  = mb * 128;
    const int n0  = nb * 128;
    const int tt0 = zz * NIT;                     // first 32-k tile of slice

    // ---- staging pointers: chunk cid in [0,512): ko=cid>>7, row=cid&127.
    // Global layout == LDS layout -> LDS offset is simply cid*16 bytes.
    const _Float16 *gpa0, *gpa1, *gpb0, *gpb1, *gpc0 = nullptr, *gpc1 = nullptr;
    int lda0, lda1, ldb0, ldb1, ldc0 = 0, ldc1 = 0;
    {
        int cid, ko, row;
        cid = tid;       ko = cid >> 7; row = cid & 127;
        gpa0 = A2 + ((size_t)(tt0 * 4 + ko) * 2048 + m0 + row) * 8;
        lda0 = cid * 16;
        cid = tid + 256; ko = cid >> 7; row = cid & 127;
        gpa1 = A2 + ((size_t)(tt0 * 4 + ko) * 2048 + m0 + row) * 8;
        lda1 = cid * 16;
        cid = tid;       ko = cid >> 7; row = cid & 127;
        gpb0 = B2 + ((size_t)(tt0 * 4 + ko) * 1024 + n0 + row) * 8;
        ldb0 = 8192 + cid * 16;
        cid = tid + 256; ko = cid >> 7; row = cid & 127;
        gpb1 = B2 + ((size_t)(tt0 * 4 + ko) * 1024 + n0 + row) * 8;
        ldb1 = 8192 + cid * 16;
        if constexpr (NPROD == 2) {
            gpc0 = gpb0 + LOPLANE; ldc0 = ldb0 + 8192;
            gpc1 = gpb1 + LOPLANE; ldc1 = ldb1 + 8192;
        }
    }

    // ---- fragment offsets: wave (wr,wc); lane: lrow = lane&31, lg = lane>>5
    const int lrow = lane & 31, lg = lane >> 5;
    const int wr = (w >> 1) * 64;
    const int wc = (w & 1) * 64;
    const int aoff00 = (0 * 2 + lg) * 2048 + (wr +  0 + lrow) * 16;  // i=0 ks=0
    const int aoff01 = (1 * 2 + lg) * 2048 + (wr +  0 + lrow) * 16;  // i=0 ks=1
    const int aoff10 = (0 * 2 + lg) * 2048 + (wr + 32 + lrow) * 16;  // i=1 ks=0
    const int aoff11 = (1 * 2 + lg) * 2048 + (wr + 32 + lrow) * 16;  // i=1 ks=1
    const int boff00 = 8192 + (0 * 2 + lg) * 2048 + (wc +  0 + lrow) * 16;
    const int boff01 = 8192 + (1 * 2 + lg) * 2048 + (wc +  0 + lrow) * 16;
    const int boff10 = 8192 + (0 * 2 + lg) * 2048 + (wc + 32 + lrow) * 16;
    const int boff11 = 8192 + (1 * 2 + lg) * 2048 + (wc + 32 + lrow) * 16;

    f32x16 acc00 = (f32x16)(0.0f), acc01 = (f32x16)(0.0f);
    f32x16 acc10 = (f32x16)(0.0f), acc11 = (f32x16)(0.0f);

    uint4 Xa0, Xa1, Xb0, Xb1, Xc0, Xc1;
    uint4 Ya0, Ya1, Yb0, Yb1, Yc0, Yc1;

#define LOADSET(P)                                                             \
    P##a0 = *(const uint4*)gpa0; gpa0 += ATILE_STRIDE;                         \
    P##a1 = *(const uint4*)gpa1; gpa1 += ATILE_STRIDE;                         \
    P##b0 = *(const uint4*)gpb0; gpb0 += BTILE_STRIDE;                         \
    P##b1 = *(const uint4*)gpb1; gpb1 += BTILE_STRIDE;                         \
    if constexpr (NPROD == 2) {                                                \
        P##c0 = *(const uint4*)gpc0; gpc0 += BTILE_STRIDE;                     \
        P##c1 = *(const uint4*)gpc1; gpc1 += BTILE_STRIDE;                     \
    }

#define STORESET(P, SB)                                                        \
    *(uint4*)((SB) + lda0) = P##a0;                                            \
    *(uint4*)((SB) + lda1) = P##a1;                                            \
    *(uint4*)((SB) + ldb0) = P##b0;                                            \
    *(uint4*)((SB) + ldb1) = P##b1;                                            \
    if constexpr (NPROD == 2) {                                                \
        *(uint4*)((SB) + ldc0) = P##c0;                                        \
        *(uint4*)((SB) + ldc1) = P##c1;                                        \
    }

#define COMPUTE(BUFI) do {                                                     \
    const char* sb = smem + (BUFI) * BUF;                                      \
    f16x8 fa00 = *(const f16x8*)(sb + aoff00);                                 \
    f16x8 fa01 = *(const f16x8*)(sb + aoff01);                                 \
    f16x8 fa10 = *(const f16x8*)(sb + aoff10);                                 \
    f16x8 fa11 = *(const f16x8*)(sb + aoff11);                                 \
    f16x8 fb00 = *(const f16x8*)(sb + boff00);                                 \
    f16x8 fb01 = *(const f16x8*)(sb + boff01);                                 \
    f16x8 fb10 = *(const f16x8*)(sb + boff10);                                 \
    f16x8 fb11 = *(const f16x8*)(sb + boff11);                                 \
    acc00 = __builtin_amdgcn_mfma_f32_32x32x16_f16(fa00, fb00, acc00, 0, 0, 0);\
    acc01 = __builtin_amdgcn_mfma_f32_32x32x16_f16(fa00, fb10, acc01, 0, 0, 0);\
    acc10 = __builtin_amdgcn_mfma_f32_32x32x16_f16(fa10, fb00, acc10, 0, 0, 0);\
    acc11 = __builtin_amdgcn_mfma_f32_32x32x16_f16(fa10, fb10, acc11, 0, 0, 0);\
    acc00 = __builtin_amdgcn_mfma_f32_32x32x16_f16(fa01, fb01, acc00, 0, 0, 0);\
    acc01 = __builtin_amdgcn_mfma_f32_32x32x16_f16(fa01, fb11, acc01, 0, 0, 0);\
    acc10 = __builtin_amdgcn_mfma_f32_32x32x16_f16(fa11, fb01, acc10, 0, 0, 0);\
    acc11 = __builtin_amdgcn_mfma_f32_32x32x16_f16(fa11, fb11, acc11, 0, 0, 0);\
    if constexpr (NPROD == 2) {                                                \
        f16x8 fc00 = *(const f16x8*)(sb + boff00 + 8192);                      \
        f16x8 fc01 = *(const f16x8*)(sb + boff01 + 8192);                      \
        f16x8 fc10 = *(const f16x8*)(sb + boff10 + 8192);                      \
        f16x8 fc11 = *(const f16x8*)(sb + boff11 + 8192);                      \
        acc00 = __builtin_amdgcn_mfma_f32_32x32x16_f16(fa00, fc00, acc00, 0, 0, 0); \
        acc01 = __builtin_amdgcn_mfma_f32_32x32x16_f16(fa00, fc10, acc01, 0, 0, 0); \
        acc10 = __builtin_amdgcn_mfma_f32_32x32x16_f16(fa10, fc00, acc10, 0, 0, 0); \
        acc11 = __builtin_amdgcn_mfma_f32_32x32x16_f16(fa10, fc10, acc11, 0, 0, 0); \
        acc00 = __builtin_amdgcn_mfma_f32_32x32x16_f16(fa01, fc01, acc00, 0, 0, 0); \
        acc01 = __builtin_amdgcn_mfma_f32_32x32x16_f16(fa01, fc11, acc01, 0, 0, 0); \
        acc10 = __builtin_amdgcn_mfma_f32_32x32x16_f16(fa11, fc01, acc10, 0, 0, 0); \
        acc11 = __builtin_amdgcn_mfma_f32_32x32x16_f16(fa11, fc11, acc11, 0, 0, 0); \
    }                                                                          \
} while (0)

    LOADSET(X)     // tile 0
    LOADSET(Y)     // tile 1
#pragma unroll 1
    for (int it = 0; it < NIT; it += 2) {
        STORESET(X, smem)                       // waits vmcnt on X
        __syncthreads();
        LOADSET(X)                              // tile it+2 (tail over-read stays in-ws)
        COMPUTE(0);
        STORESET(Y, smem + BUF)
        __syncthreads();
        LOADSET(Y)                              // tile it+3
        COMPUTE(1);
    }
#undef LOADSET
#undef STORESET
#undef COMPUTE

    // ---- epilogue: 32x32 C layout: col=lane&31, row=(r&3)+8*(r>>2)+4*lg ----
    float* Cs = Cp + (size_t)zz * CSZ;
    const int col0 = n0 + wc + lrow;
#pragma unroll
    for (int r = 0; r < 16; ++r) {
        const int rp = (r & 3) + 8 * (r >> 2) + 4 * lg;
        Cs[(size_t)(m0 + wr + rp) * HCOLS + col0]           = acc00[r];
        Cs[(size_t)(m0 + wr + rp) * HCOLS + col0 + 32]      = acc01[r];
        Cs[(size_t)(m0 + wr + 32 + rp) * HCOLS + col0]      = acc10[r];
        Cs[(size_t)(m0 + wr + 32 + rp) * HCOLS + col0 + 32] = acc11[r];
    }
}

// ---------------------------------------------------------------------------
// Kernel 3b: AX = sum of KSPLIT k-slice partials (one-time, x path)
// ---------------------------------------------------------------------------
__global__ __launch_bounds__(256) void reduce_ax(const float* __restrict__ P,
                                                 float* __restrict__ AX) {
    const size_t idx = (size_t)blockIdx.x * 256 + threadIdx.x;
    const float4* P4 = (const float4*)P;
    const size_t q = CSZ / 4;
    float4 a = P4[idx], b = P4[idx + q], c = P4[idx + 2 * q], d = P4[idx + 3 * q];
    float4 r;
    r.x = a.x + b.x + c.x + d.x;
    r.y = a.y + b.y + c.y + d.y;
    r.z = a.z + b.z + c.z + d.z;
    r.w = a.w + b.w + c.w + d.w;
    ((float4*)AX)[idx] = r;
}

// ---------------------------------------------------------------------------
// Kernel 3c: weight prep. Whr[k][h][g] = Wh[k][g*32+h]; Wxr[c][h][g]; bfold.
// ---------------------------------------------------------------------------
__global__ __launch_bounds__(256) void prep_weights(const float* __restrict__ Wx,
                                                    const float* __restrict__ bx,
                                                    const float* __restrict__ Wh,
                                                    const float* __restrict__ bh,
                                                    float* __restrict__ Whr,
                                                    float* __restrict__ Wxr,
                                                    float* __restrict__ bfold) {
    const int tid = threadIdx.x;
#pragma unroll
    for (int r = 0; r < 16; ++r) {
        const int idx = tid * 16 + r;           // 4096
        const int k = idx >> 7, rem = idx & 127;
        const int h = rem >> 2, g = rem & 3;
        Whr[idx] = Wh[k * GC + g * HH + h];
    }
    {
        const int idx = tid;                    // 256
        const int c = idx >> 7, rem = idx & 127;
        const int h = rem >> 2, g = rem & 3;
        Wxr[idx] = Wx[c * GC + g * HH + h];
    }
    if (tid < 128) {
        const int h = tid >> 2, g = tid & 3;
        bfold[tid] = bx[g * HH + h] + bh[g * HH + h];
    }
}

// ---------------------------------------------------------------------------
// Kernel 4: gates + cell update, 64 nodes x 4 batches per block.
// Reads KSPLIT k-slice partials inline; writes h32 and hT (tiled fp16).
// ---------------------------------------------------------------------------
__global__ __launch_bounds__(256) void gate_update(const float* __restrict__ AX,
                                                   const float* __restrict__ Ahp,
                                                   const float* __restrict__ Whr,
                                                   const float* __restrict__ Wxr,
                                                   const float* __restrict__ bfold,
                                                   float* __restrict__ c,
                                                   float* __restrict__ h32,
                                                   _Float16* __restrict__ hT,
                                                   int t, int first) {
    const int n0 = blockIdx.x * 64;
    const int b0 = blockIdx.y * 4;
    const int tid = threadIdx.x;
    __shared__ float whr[4096];
    __shared__ float wxr[256];
    __shared__ float bfl[128];
    __shared__ float ah_s[64][33];
    __shared__ float axs[2][64];

#pragma unroll
    for (int r = 0; r < 4; ++r)
        *(float4*)&whr[(tid * 4 + r * 1024)] = *(const float4*)&Whr[(tid * 4 + r * 1024)];
    if (tid < 64)  *(float4*)&wxr[tid * 4] = *(const float4*)&Wxr[tid * 4];
    if (tid < 32)  *(float4*)&bfl[tid * 4] = *(const float4*)&bfold[tid * 4];

    const int nl = tid & 63;
    const int hq = tid >> 6;

    // tiled-hT base for this thread's node (col stride is 8 elements)
    const int nd = n0 + nl;
    const size_t ntbase = ((size_t)((nd >> 5) * 4 + ((nd >> 3) & 3)) * 1024) * 8 + (nd & 7);

#pragma unroll 1
    for (int bi = 0; bi < 4; ++bi) {
        const int b = b0 + bi;
        if (bi) __syncthreads();

        if (!first) {
            const int nls = tid >> 2;
            const int kq = (tid & 3) * 8;
            float4 a0 = make_float4(0, 0, 0, 0), a1 = make_float4(0, 0, 0, 0);
#pragma unroll
            for (int s = 0; s < KSPLIT; ++s) {
                const float* src = Ahp + s * CSZ + (size_t)(n0 + nls) * HCOLS + b * HH + kq;
                const float4 v0 = *(const float4*)src;
                const float4 v1 = *(const float4*)(src + 4);
                a0.x += v0.x; a0.y += v0.y; a0.z += v0.z; a0.w += v0.w;
                a1.x += v1.x; a1.y += v1.y; a1.z += v1.z; a1.w += v1.w;
            }
            ah_s[nls][kq + 0] = a0.x; ah_s[nls][kq + 1] = a0.y;
            ah_s[nls][kq + 2] = a0.z; ah_s[nls][kq + 3] = a0.w;
            ah_s[nls][kq + 4] = a1.x; ah_s[nls][kq + 5] = a1.y;
            ah_s[nls][kq + 6] = a1.z; ah_s[nls][kq + 7] = a1.w;
        }
        if (tid < 128) {
            const int which = tid >> 6, nls = tid & 63;
            axs[which][nls] = AX[(size_t)(n0 + nls) * XCOLS + (b * TT + t) * CIN + which];
        }
        __syncthreads();

        const float ax0 = axs[0][nl], ax1 = axs[1][nl];
        float acc[8][4];
#pragma unroll
        for (int u = 0; u < 8; ++u) {
            const int h = hq * 8 + u;
#pragma unroll
            for (int g = 0; g < 4; ++g)
                acc[u][g] = bfl[h * 4 + g] + ax0 * wxr[h * 4 + g] + ax1 * wxr[128 + h * 4 + g];
        }
        if (!first) {
            float ah_r[HH];
#pragma unroll
            for (int k = 0; k < HH; ++k) ah_r[k] = ah_s[nl][k];
#pragma unroll 4
            for (int k = 0; k < HH; ++k) {
                const float a = ah_r[k];
#pragma unroll
                for (int u = 0; u < 8; ++u) {
                    const float* wp = &whr[(k * HH + hq * 8 + u) * 4];
                    acc[u][0] += a * wp[0];
                    acc[u][1] += a * wp[1];
                    acc[u][2] += a * wp[2];
                    acc[u][3] += a * wp[3];
                }
            }
        }

        float cn[8], hn[8];
        const size_t off = (size_t)(n0 + nl) * HCOLS + b * HH + hq * 8;
        float4 c0o = make_float4(0, 0, 0, 0), c1o = make_float4(0, 0, 0, 0);
        if (!first) { c0o = *(const float4*)(c + off); c1o = *(const float4*)(c + off + 4); }
        const float cold[8] = {c0o.x, c0o.y, c0o.z, c0o.w, c1o.x, c1o.y, c1o.z, c1o.w};
#pragma unroll
        for (int u = 0; u < 8; ++u) {
            const float i_ = 1.0f / (1.0f + expf(-acc[u][0]));
            const float f_ = 1.0f / (1.0f + expf(-acc[u][1]));
            const float o_ = 1.0f / (1.0f + expf(-acc[u][2]));
            const float g_ = tanhf(acc[u][3]);
            const float c_t = f_ * cold[u] + i_ * g_;
            cn[u] = c_t;
            hn[u] = o_ * tanhf(c_t);
        }
        *(float4*)(c + off)       = make_float4(cn[0], cn[1], cn[2], cn[3]);
        *(float4*)(c + off + 4)   = make_float4(cn[4], cn[5], cn[6], cn[7]);
        *(float4*)(h32 + off)     = make_float4(hn[0], hn[1], hn[2], hn[3]);
        *(float4*)(h32 + off + 4) = make_float4(hn[4], hn[5], hn[6], hn[7]);
#pragma unroll
        for (int u = 0; u < 8; ++u)
            hT[ntbase + (size_t)(b * HH + hq * 8 + u) * 8] = (_Float16)hn[u];
    }
}

// ---------------------------------------------------------------------------
// Kernel 5: out[b][th][n] = bp[th] + sum_k h[n][b*H+k] * Wp[k][th]
// ---------------------------------------------------------------------------
__global__ __launch_bounds__(256) void head_kernel(const float* __restrict__ h,
                                                   const float* __restrict__ Wp,
                                                   const float* __restrict__ bp,
                                                   float* __restrict__ out) {
    const int idx = blockIdx.x * 256 + threadIdx.x;
    const int b = idx >> 11;
    const int n = idx & (NN - 1);
    float hv[HH];
    const float* hp = h + (size_t)n * HCOLS + b * HH;
#pragma unroll
    for (int k = 0; k < HH; ++k) hv[k] = hp[k];
#pragma unroll
    for (int th = 0; th < HOR; ++th) {
        float acc = bp[th];
#pragma unroll
        for (int k = 0; k < HH; ++k) acc += hv[k] * Wp[k * HOR + th];
        out[((size_t)b * HOR + th) * NN + n] = acc;
    }
}

// ---------------------------------------------------------------------------
extern "C" void kernel_launch(void* const* d_in, const int* in_sizes, int n_in,
                              void* d_out, int out_size, void* d_ws, size_t ws_size,
                              hipStream_t stream) {
    const float* x  = (const float*)d_in[0];
    const float* E1 = (const float*)d_in[1];
    const float* E2 = (const float*)d_in[2];
    const float* Wx = (const float*)d_in[3];
    const float* bx = (const float*)d_in[4];
    const float* Wh = (const float*)d_in[5];
    const float* bh = (const float*)d_in[6];
    const float* Wp = (const float*)d_in[7];
    const float* bp = (const float*)d_in[8];

    char* ws = (char*)d_ws;
    _Float16* A2  = (_Float16*)(ws);                    //  8 MB  tiled A
    _Float16* B2x = (_Float16*)(ws + ( 8ull << 20));    //  8 MB  tiled x hi/lo
    _Float16* hT  = (_Float16*)(ws + (16ull << 20));    //  4 MB  tiled h
    float* P    = (float*)(ws + (20ull << 20));         // 32 MB  (4 k-slice partials)
    float* AX   = (float*)(ws + (52ull << 20));         //  8 MB
    float* cst  = (float*)(ws + (60ull << 20));         //  8 MB
    float* h32  = (float*)(ws + (68ull << 20));         //  8 MB
    float* Whr  = (float*)(ws + (76ull << 20));         // 16 KB
    float* Wxr  = (float*)(ws + (76ull << 20) + 65536);
    float* bfold= (float*)(ws + (76ull << 20) + 131072);

    adj_softmax<<<NN, 256, 0, stream>>>(E1, E2, A2);
    transpose_x<<<(XCOLS * NN) / 256, 256, 0, stream>>>(x, B2x);
    prep_weights<<<1, 256, 0, stream>>>(Wx, bx, Wh, bh, Whr, Wxr, bfold);

    gemm_f16<2><<<512, 256, 0, stream>>>(A2, B2x, P);     // x path: hi+lo
    reduce_ax<<<(int)(CSZ / 4 / 256), 256, 0, stream>>>(P, AX);

    for (int t = 0; t < TT; ++t) {
        if (t > 0)
            gemm_f16<1><<<512, 256, 0, stream>>>(A2, hT, P);   // recurrent
        gate_update<<<dim3(NN / 64, BB / 4), 256, 0, stream>>>(AX, P, Whr, Wxr, bfold,
                                                               cst, h32, hT, t, t == 0 ? 1 : 0);
    }

    head_kernel<<<(BB * NN) / 256, 256, 0, stream>>>(h32, Wp, bp, (float*)d_out);
}

// Round 2
// 882.925 us; speedup vs baseline: 1.2249x; 1.0659x over previous
//
#include <hip/hip_runtime.h>
#include <hip/hip_bf16.h>
#include <cstddef>
#include <cstdint>

#define NN 2048      // nodes (M and K of the big GEMMs)
#define CIN 2
#define HH 32        // hidden
#define EMB 16
#define HOR 12
#define BB 32        // batch
#define TT 16        // time steps
#define GC 128       // 4*HH gate channels
#define XCOLS 1024   // B*T*C
#define HCOLS 1024   // B*H  (GEMM N dim)
#define NT2 64       // full-K: 2048/32 K-tiles (BK=32)

// Tiled fp16 operand layouts (32-k tiles, 8-elem chunks), matching the GEMM's
// LDS layout exactly so staging is a LINEAR contiguous copy:
//   A2t [tt=64][ko=4][row=2048][e=8] : elem ((tt*4+ko)*2048+row)*8+e = A[row][tt*32+ko*8+e]
//   hTt [tt=64][ko=4][col=1024][e=8] : elem ((tt*4+ko)*1024+col)*8+e = h[node=tt*32+ko*8+e][col]
//   B2xt: hi plane same shape as hTt; lo plane at +LOPLANE elements.
#define ATILE_STRIDE 65536   // 4*2048*8 elements per 32-k tile of A
#define BTILE_STRIDE 32768   // 4*1024*8 elements per 32-k tile of B
#define LOPLANE 2097152      // elements per x plane (64*4*1024*8)

typedef __attribute__((ext_vector_type(8))) _Float16 f16x8;
typedef __attribute__((ext_vector_type(16))) float f32x16;

// ---------------------------------------------------------------------------
// Kernel 1: A = softmax(relu(E1 @ E2^T)) -> A2t tiled fp16
// ---------------------------------------------------------------------------
__global__ __launch_bounds__(256) void adj_softmax(const float* __restrict__ E1,
                                                   const float* __restrict__ E2,
                                                   _Float16* __restrict__ A2) {
    const int i = blockIdx.x;
    __shared__ float red[256];
    float e1[EMB];
#pragma unroll
    for (int k = 0; k < EMB; ++k) e1[k] = E1[i * EMB + k];

    float s[8];
    float mx = -1e30f;
#pragma unroll
    for (int q = 0; q < 8; ++q) {
        const int j = q * 256 + threadIdx.x;
        float d = 0.f;
#pragma unroll
        for (int k = 0; k < EMB; ++k) d += e1[k] * E2[j * EMB + k];
        d = fmaxf(d, 0.0f);
        s[q] = d;
        mx = fmaxf(mx, d);
    }
    red[threadIdx.x] = mx;
    __syncthreads();
    for (int off = 128; off > 0; off >>= 1) {
        if (threadIdx.x < off) red[threadIdx.x] = fmaxf(red[threadIdx.x], red[threadIdx.x + off]);
        __syncthreads();
    }
    mx = red[0];
    __syncthreads();

    float sum = 0.f;
#pragma unroll
    for (int q = 0; q < 8; ++q) { s[q] = expf(s[q] - mx); sum += s[q]; }
    red[threadIdx.x] = sum;
    __syncthreads();
    for (int off = 128; off > 0; off >>= 1) {
        if (threadIdx.x < off) red[threadIdx.x] += red[threadIdx.x + off];
        __syncthreads();
    }
    const float inv = 1.0f / red[0];
#pragma unroll
    for (int q = 0; q < 8; ++q) {
        const int j  = q * 256 + threadIdx.x;      // k-index of A row i
        const int tt = j >> 5, ko = (j >> 3) & 3, e = j & 7;
        A2[((size_t)(tt * 4 + ko) * 2048 + i) * 8 + e] = (_Float16)(s[q] * inv);
    }
}

// ---------------------------------------------------------------------------
// Kernel 2: x -> B2xt tiled hi/lo fp16 planes (col = (b*T+t)*C + c).
// ---------------------------------------------------------------------------
__global__ __launch_bounds__(256) void transpose_x(const float* __restrict__ x,
                                                   _Float16* __restrict__ B2x) {
    const int idx = blockIdx.x * 256 + threadIdx.x;
    const int col = idx >> 11;
    const int j   = idx & (NN - 1);               // node index (gemm K dim)
    const int bt  = col >> 1;
    const int c   = col & 1;
    const float v = x[((size_t)bt * NN + j) * CIN + c];
    const _Float16 hi = (_Float16)v;
    const _Float16 lo = (_Float16)(v - (float)hi);
    const int tt = j >> 5, ko = (j >> 3) & 3, e = j & 7;
    const size_t base = ((size_t)(tt * 4 + ko) * 1024 + col) * 8 + e;
    B2x[base] = hi; B2x[base + LOPLANE] = lo;
}

// ---------------------------------------------------------------------------
// Kernel 3: fused full-K fp16 MFMA GEMM (32x32x16) + optional gate epilogue.
// Tile M=32 nodes x N=128 cols, K=2048 (no split-K -> no partial buffer).
// Grid 512 = 64 mb x 8 nb, 2 blocks/CU. 4 waves, each one 32x32 acc
// (wave w owns cols w*32..w*32+31; A fragments broadcast across waves).
// XCD swizzle: physical XCD x owns mb in [x*8, x*8+8) x all nb -> A slab
// (1 MB) and this slab's c-state stay in that XCD's L2 across timesteps.
// GATE=0: store C directly (AX path; NPROD=2 sums hi+lo planes into acc).
// GATE=1: epilogue computes gates = C*Whr + AX*Wxr + b, LSTM cell update,
//         writes c, tiled hT (ping-pong buffer), h32 on last step.
// ---------------------------------------------------------------------------
template <int NPROD, int GATE>
__global__ __launch_bounds__(256, 2) void gemm_fused(const _Float16* __restrict__ A2,
                                                     const _Float16* __restrict__ B2,
                                                     float* __restrict__ Cout,
                                                     const float* __restrict__ AX,
                                                     const float* __restrict__ Whr,
                                                     const float* __restrict__ Wxr,
                                                     const float* __restrict__ bfold,
                                                     float* __restrict__ cst,
                                                     float* __restrict__ h32,
                                                     _Float16* __restrict__ hTout,
                                                     int t, int last) {
    constexpr int BUF = 2048 + NPROD * 8192;       // A 2KB + B planes
    constexpr int STAGE = 2 * BUF;
    constexpr int SMEMSZ = GATE ? (STAGE + 16384 + 1024 + 512 + 1024) : STAGE;
    __shared__ __align__(16) char smem[SMEMSZ];

    const int tid  = threadIdx.x;
    const int w    = tid >> 6;
    const int lane = tid & 63;

    // XCD-aware decomposition: physical XCD = wg & 7 (round-robin dispatch).
    const int wg = blockIdx.x;
    const int x8 = wg & 7;
    const int s  = wg >> 3;            // 0..63
    const int mb = x8 * 8 + (s & 7);   // XCD owns 8 consecutive m-blocks
    const int nb = s >> 3;             // 0..7
    const int m0 = mb * 32;
    const int n0 = nb * 128;

    float* whr_s = nullptr; float* wxr_s = nullptr; float* bfl_s = nullptr; float* axs = nullptr;
    if constexpr (GATE) {
        whr_s = (float*)(smem + STAGE);
        wxr_s = whr_s + 4096;
        bfl_s = wxr_s + 256;
        axs   = bfl_s + 128;           // [bi 4][which 2][nl 32]
        const int b0c = nb * 4;
#pragma unroll
        for (int r = 0; r < 4; ++r)
            *(float4*)&whr_s[tid * 4 + r * 1024] = *(const float4*)&Whr[tid * 4 + r * 1024];
        if (tid < 64) *(float4*)&wxr_s[tid * 4] = *(const float4*)&Wxr[tid * 4];
        if (tid < 32) *(float4*)&bfl_s[tid * 4] = *(const float4*)&bfold[tid * 4];
        axs[tid] = AX[(size_t)(m0 + (tid & 31)) * XCOLS +
                      ((b0c + (tid >> 6)) * TT + t) * CIN + ((tid >> 5) & 1)];
    }

    // ---- staging: A 128 chunks (tid<128), B 512 chunks (tid, tid+256).
    // Global tiled layout == LDS layout -> LDS offset = chunk*16 bytes.
    const int cidA = tid & 127;
    const _Float16* gpa0 = A2 + ((size_t)((cidA >> 5)) * 2048 + m0 + (cidA & 31)) * 8;
    const int lda0 = cidA * 16;
    const _Float16* gpb0 = B2 + ((size_t)(tid >> 7) * 1024 + n0 + (tid & 127)) * 8;
    const int ldb0 = 2048 + tid * 16;
    const _Float16* gpb1 = B2 + ((size_t)((tid + 256) >> 7) * 1024 + n0 + ((tid + 256) & 127)) * 8;
    const int ldb1 = 2048 + (tid + 256) * 16;
    const _Float16 *gpc0 = nullptr, *gpc1 = nullptr;
    int ldc0 = 0, ldc1 = 0;
    if constexpr (NPROD == 2) {
        gpc0 = gpb0 + LOPLANE; ldc0 = ldb0 + 8192;
        gpc1 = gpb1 + LOPLANE; ldc1 = ldb1 + 8192;
    }

    // ---- fragment offsets: lane lrow = lane&31, lg = lane>>5; wave cols w*32
    const int lrow = lane & 31, lg = lane >> 5;
    const int wc = w * 32;
    const int aoff0 = lg * 512 + lrow * 16;               // ks=0 (ko = lg)
    const int aoff1 = 1024 + lg * 512 + lrow * 16;        // ks=1 (ko = 2+lg)
    const int boff0 = 2048 + lg * 2048 + (wc + lrow) * 16;
    const int boff1 = 2048 + 4096 + lg * 2048 + (wc + lrow) * 16;

    f32x16 acc = (f32x16)(0.0f);

    uint4 Xa0, Xb0, Xb1, Xc0, Xc1;
    uint4 Ya0, Yb0, Yb1, Yc0, Yc1;

#define LOADSET(P)                                                             \
    if (tid < 128) { P##a0 = *(const uint4*)gpa0; }                            \
    gpa0 += ATILE_STRIDE;                                                      \
    P##b0 = *(const uint4*)gpb0; gpb0 += BTILE_STRIDE;                         \
    P##b1 = *(const uint4*)gpb1; gpb1 += BTILE_STRIDE;                         \
    if constexpr (NPROD == 2) {                                                \
        P##c0 = *(const uint4*)gpc0; gpc0 += BTILE_STRIDE;                     \
        P##c1 = *(const uint4*)gpc1; gpc1 += BTILE_STRIDE;                     \
    }

#define STORESET(P, SB)                                                        \
    if (tid < 128) { *(uint4*)((SB) + lda0) = P##a0; }                         \
    *(uint4*)((SB) + ldb0) = P##b0;                                            \
    *(uint4*)((SB) + ldb1) = P##b1;                                            \
    if constexpr (NPROD == 2) {                                                \
        *(uint4*)((SB) + ldc0) = P##c0;                                        \
        *(uint4*)((SB) + ldc1) = P##c1;                                        \
    }

#define COMPUTE(BUFI) do {                                                     \
    const char* sb = smem + (BUFI) * BUF;                                      \
    f16x8 fa0 = *(const f16x8*)(sb + aoff0);                                   \
    f16x8 fa1 = *(const f16x8*)(sb + aoff1);                                   \
    f16x8 fb0 = *(const f16x8*)(sb + boff0);                                   \
    f16x8 fb1 = *(const f16x8*)(sb + boff1);                                   \
    acc = __builtin_amdgcn_mfma_f32_32x32x16_f16(fa0, fb0, acc, 0, 0, 0);      \
    acc = __builtin_amdgcn_mfma_f32_32x32x16_f16(fa1, fb1, acc, 0, 0, 0);      \
    if constexpr (NPROD == 2) {                                                \
        f16x8 fc0 = *(const f16x8*)(sb + boff0 + 8192);                        \
        f16x8 fc1 = *(const f16x8*)(sb + boff1 + 8192);                        \
        acc = __builtin_amdgcn_mfma_f32_32x32x16_f16(fa0, fc0, acc, 0, 0, 0);  \
        acc = __builtin_amdgcn_mfma_f32_32x32x16_f16(fa1, fc1, acc, 0, 0, 0);  \
    }                                                                          \
} while (0)

    LOADSET(X)     // tile 0
    LOADSET(Y)     // tile 1
#pragma unroll 1
    for (int it = 0; it < NT2; it += 2) {
        STORESET(X, smem)                       // waits vmcnt on X
        __syncthreads();
        LOADSET(X)                              // tile it+2 (tail over-read stays in-ws)
        COMPUTE(0);
        STORESET(Y, smem + BUF)
        __syncthreads();
        LOADSET(Y)                              // tile it+3
        COMPUTE(1);
    }
#undef LOADSET
#undef STORESET
#undef COMPUTE

    // ---- C layout per 32x32 acc: col=lane&31, row=(r&3)+8*(r>>2)+4*lg ----
    if constexpr (!GATE) {
        const int colg = n0 + wc + lrow;
#pragma unroll
        for (int r = 0; r < 16; ++r) {
            const int rp = (r & 3) + 8 * (r >> 2) + 4 * lg;
            Cout[(size_t)(m0 + rp) * XCOLS + colg] = acc[r];
        }
    } else {
        // stage Ah tile to LDS (overlays staging buffers)
        __syncthreads();
        float* ah = (float*)smem;               // [32][129]
#pragma unroll
        for (int r = 0; r < 16; ++r) {
            const int rp = (r & 3) + 8 * (r >> 2) + 4 * lg;
            ah[rp * 129 + wc + lrow] = acc[r];
        }
        __syncthreads();

        const int nl2 = tid & 31;               // node within tile
        const int hq  = tid >> 5;               // 0..7 -> h = hq*4+u
        const int b0c = nb * 4;
        const int nd  = m0 + nl2;
        const size_t ntbase = ((size_t)((nd >> 5) * 4 + ((nd >> 3) & 3)) * 1024) * 8 + (nd & 7);

#pragma unroll 1
        for (int bi = 0; bi < 4; ++bi) {
            const float ax0 = axs[bi * 64 + nl2];
            const float ax1 = axs[bi * 64 + 32 + nl2];
            float ar[32];
#pragma unroll
            for (int k = 0; k < 32; ++k) ar[k] = ah[nl2 * 129 + bi * 32 + k];

            float a4[4][4];
#pragma unroll
            for (int u = 0; u < 4; ++u) {
                const int h = hq * 4 + u;
#pragma unroll
                for (int g = 0; g < 4; ++g)
                    a4[u][g] = bfl_s[h * 4 + g] + ax0 * wxr_s[h * 4 + g] + ax1 * wxr_s[128 + h * 4 + g];
            }
#pragma unroll 4
            for (int k = 0; k < 32; ++k) {
                const float av = ar[k];
#pragma unroll
                for (int u = 0; u < 4; ++u) {
                    const float* wp = &whr_s[(k * 32 + hq * 4 + u) * 4];
                    a4[u][0] += av * wp[0];
                    a4[u][1] += av * wp[1];
                    a4[u][2] += av * wp[2];
                    a4[u][3] += av * wp[3];
                }
            }

            const int b = b0c + bi;
            const size_t off = (size_t)nd * HCOLS + b * HH + hq * 4;
            const float4 co = *(const float4*)(cst + off);
            const float cold[4] = {co.x, co.y, co.z, co.w};
            float cn[4], hn[4];
#pragma unroll
            for (int u = 0; u < 4; ++u) {
                const float i_ = 1.0f / (1.0f + expf(-a4[u][0]));
                const float f_ = 1.0f / (1.0f + expf(-a4[u][1]));
                const float o_ = 1.0f / (1.0f + expf(-a4[u][2]));
                const float g_ = tanhf(a4[u][3]);
                const float ct = f_ * cold[u] + i_ * g_;
                cn[u] = ct;
                hn[u] = o_ * tanhf(ct);
            }
            *(float4*)(cst + off) = make_float4(cn[0], cn[1], cn[2], cn[3]);
            if (last) *(float4*)(h32 + off) = make_float4(hn[0], hn[1], hn[2], hn[3]);
#pragma unroll
            for (int u = 0; u < 4; ++u)
                hTout[ntbase + (size_t)(b * HH + hq * 4 + u) * 8] = (_Float16)hn[u];
        }
    }
}

// ---------------------------------------------------------------------------
// Kernel 3c: weight prep. Whr[k][h][g] = Wh[k][g*32+h]; Wxr[c][h][g]; bfold.
// ---------------------------------------------------------------------------
__global__ __launch_bounds__(256) void prep_weights(const float* __restrict__ Wx,
                                                    const float* __restrict__ bx,
                                                    const float* __restrict__ Wh,
                                                    const float* __restrict__ bh,
                                                    float* __restrict__ Whr,
                                                    float* __restrict__ Wxr,
                                                    float* __restrict__ bfold) {
    const int tid = threadIdx.x;
#pragma unroll
    for (int r = 0; r < 16; ++r) {
        const int idx = tid * 16 + r;           // 4096
        const int k = idx >> 7, rem = idx & 127;
        const int h = rem >> 2, g = rem & 3;
        Whr[idx] = Wh[k * GC + g * HH + h];
    }
    {
        const int idx = tid;                    // 256
        const int c = idx >> 7, rem = idx & 127;
        const int h = rem >> 2, g = rem & 3;
        Wxr[idx] = Wx[c * GC + g * HH + h];
    }
    if (tid < 128) {
        const int h = tid >> 2, g = tid & 3;
        bfold[tid] = bx[g * HH + h] + bh[g * HH + h];
    }
}

// ---------------------------------------------------------------------------
// Kernel 4: t=0 gate update only (no recurrent term), 64 nodes x 4 batches.
// ---------------------------------------------------------------------------
__global__ __launch_bounds__(256) void gate_update(const float* __restrict__ AX,
                                                   const float* __restrict__ Whr,
                                                   const float* __restrict__ Wxr,
                                                   const float* __restrict__ bfold,
                                                   float* __restrict__ c,
                                                   float* __restrict__ h32,
                                                   _Float16* __restrict__ hT) {
    const int n0 = blockIdx.x * 64;
    const int b0 = blockIdx.y * 4;
    const int tid = threadIdx.x;
    __shared__ float wxr[256];
    __shared__ float bfl[128];
    __shared__ float axs[2][64];

    if (tid < 64)  *(float4*)&wxr[tid * 4] = *(const float4*)&Wxr[tid * 4];
    if (tid < 32)  *(float4*)&bfl[tid * 4] = *(const float4*)&bfold[tid * 4];

    const int nl = tid & 63;
    const int hq = tid >> 6;

    const int nd = n0 + nl;
    const size_t ntbase = ((size_t)((nd >> 5) * 4 + ((nd >> 3) & 3)) * 1024) * 8 + (nd & 7);

#pragma unroll 1
    for (int bi = 0; bi < 4; ++bi) {
        const int b = b0 + bi;
        if (bi) __syncthreads();
        if (tid < 128) {
            const int which = tid >> 6, nls = tid & 63;
            axs[which][nls] = AX[(size_t)(n0 + nls) * XCOLS + (b * TT + 0) * CIN + which];
        }
        __syncthreads();

        const float ax0 = axs[0][nl], ax1 = axs[1][nl];
        float cn[8], hn[8];
#pragma unroll
        for (int u = 0; u < 8; ++u) {
            const int h = hq * 8 + u;
            float a0 = bfl[h * 4 + 0] + ax0 * wxr[h * 4 + 0] + ax1 * wxr[128 + h * 4 + 0];
            float a1 = bfl[h * 4 + 1] + ax0 * wxr[h * 4 + 1] + ax1 * wxr[128 + h * 4 + 1];
            float a2 = bfl[h * 4 + 2] + ax0 * wxr[h * 4 + 2] + ax1 * wxr[128 + h * 4 + 2];
            float a3 = bfl[h * 4 + 3] + ax0 * wxr[h * 4 + 3] + ax1 * wxr[128 + h * 4 + 3];
            const float i_ = 1.0f / (1.0f + expf(-a0));
            const float f_ = 1.0f / (1.0f + expf(-a1));
            const float o_ = 1.0f / (1.0f + expf(-a2));
            const float g_ = tanhf(a3);
            const float ct = i_ * g_;          // c_old = 0
            (void)f_;
            cn[u] = ct;
            hn[u] = o_ * tanhf(ct);
        }
        const size_t off = (size_t)nd * HCOLS + b * HH + hq * 8;
        *(float4*)(c + off)       = make_float4(cn[0], cn[1], cn[2], cn[3]);
        *(float4*)(c + off + 4)   = make_float4(cn[4], cn[5], cn[6], cn[7]);
        *(float4*)(h32 + off)     = make_float4(hn[0], hn[1], hn[2], hn[3]);
        *(float4*)(h32 + off + 4) = make_float4(hn[4], hn[5], hn[6], hn[7]);
#pragma unroll
        for (int u = 0; u < 8; ++u)
            hT[ntbase + (size_t)(b * HH + hq * 8 + u) * 8] = (_Float16)hn[u];
    }
}

// ---------------------------------------------------------------------------
// Kernel 5: out[b][th][n] = bp[th] + sum_k h[n][b*H+k] * Wp[k][th]
// ---------------------------------------------------------------------------
__global__ __launch_bounds__(256) void head_kernel(const float* __restrict__ h,
                                                   const float* __restrict__ Wp,
                                                   const float* __restrict__ bp,
                                                   float* __restrict__ out) {
    const int idx = blockIdx.x * 256 + threadIdx.x;
    const int b = idx >> 11;
    const int n = idx & (NN - 1);
    float hv[HH];
    const float* hp = h + (size_t)n * HCOLS + b * HH;
#pragma unroll
    for (int k = 0; k < HH; ++k) hv[k] = hp[k];
#pragma unroll
    for (int th = 0; th < HOR; ++th) {
        float acc = bp[th];
#pragma unroll
        for (int k = 0; k < HH; ++k) acc += hv[k] * Wp[k * HOR + th];
        out[((size_t)b * HOR + th) * NN + n] = acc;
    }
}

// ---------------------------------------------------------------------------
extern "C" void kernel_launch(void* const* d_in, const int* in_sizes, int n_in,
                              void* d_out, int out_size, void* d_ws, size_t ws_size,
                              hipStream_t stream) {
    const float* x  = (const float*)d_in[0];
    const float* E1 = (const float*)d_in[1];
    const float* E2 = (const float*)d_in[2];
    const float* Wx = (const float*)d_in[3];
    const float* bx = (const float*)d_in[4];
    const float* Wh = (const float*)d_in[5];
    const float* bh = (const float*)d_in[6];
    const float* Wp = (const float*)d_in[7];
    const float* bp = (const float*)d_in[8];

    char* ws = (char*)d_ws;
    _Float16* A2  = (_Float16*)(ws);                    //  8 MB  tiled A
    _Float16* B2x = (_Float16*)(ws + ( 8ull << 20));    //  8 MB  tiled x hi/lo
    _Float16* hT0 = (_Float16*)(ws + (16ull << 20));    //  4 MB  tiled h (ping)
    _Float16* hT1 = (_Float16*)(ws + (20ull << 20));    //  4 MB  tiled h (pong)
    float* AX   = (float*)(ws + (24ull << 20));         //  8 MB
    float* cst  = (float*)(ws + (32ull << 20));         //  8 MB
    float* h32  = (float*)(ws + (40ull << 20));         //  8 MB
    float* Whr  = (float*)(ws + (48ull << 20));         // 16 KB
    float* Wxr  = (float*)(ws + (48ull << 20) + 65536);
    float* bfold= (float*)(ws + (48ull << 20) + 131072);
    _Float16* hTb[2] = {hT0, hT1};

    adj_softmax<<<NN, 256, 0, stream>>>(E1, E2, A2);
    transpose_x<<<(XCOLS * NN) / 256, 256, 0, stream>>>(x, B2x);
    prep_weights<<<1, 256, 0, stream>>>(Wx, bx, Wh, bh, Whr, Wxr, bfold);

    // x path: AX = A*Xhi + A*Xlo, written directly (no partials)
    gemm_fused<2, 0><<<512, 256, 0, stream>>>(A2, B2x, AX, nullptr, nullptr, nullptr,
                                              nullptr, nullptr, nullptr, nullptr, 0, 0);

    // t = 0: gates from AX only
    gate_update<<<dim3(NN / 64, BB / 4), 256, 0, stream>>>(AX, Whr, Wxr, bfold,
                                                           cst, h32, hTb[0]);
    // t = 1..15: fused GEMM + gate epilogue; hT ping-pong (read prev, write cur)
    for (int t = 1; t < TT; ++t) {
        gemm_fused<1, 1><<<512, 256, 0, stream>>>(A2, hTb[(t + 1) & 1], nullptr, AX,
                                                  Whr, Wxr, bfold, cst, h32,
                                                  hTb[t & 1], t, t == TT - 1 ? 1 : 0);
    }

    head_kernel<<<(BB * NN) / 256, 256, 0, stream>>>(h32, Wp, bp, (float*)d_out);
}

// Round 3
// 727.074 us; speedup vs baseline: 1.4875x; 1.2144x over previous
//
#include <hip/hip_runtime.h>
#include <hip/hip_bf16.h>
#include <cstddef>
#include <cstdint>

#define NN 2048      // nodes (M and K of the big GEMMs)
#define CIN 2
#define HH 32        // hidden
#define EMB 16
#define HOR 12
#define BB 32        // batch
#define TT 16        // time steps
#define GC 128       // 4*HH gate channels
#define XCOLS 1024   // B*T*C
#define HCOLS 1024   // B*H  (GEMM N dim)
#define NT2 64       // full-K: 2048/32 K-tiles (BK=32)

// Tiled fp16 operand layouts (32-k tiles, 8-elem chunks), matching the GEMM's
// LDS layout exactly so staging is a LINEAR contiguous copy:
//   A2t [tt=64][ko=4][row=2048][e=8] : elem ((tt*4+ko)*2048+row)*8+e = A[row][tt*32+ko*8+e]
//   hTt [tt=64][ko=4][col=1024][e=8] : elem ((tt*4+ko)*1024+col)*8+e = h[node=tt*32+ko*8+e][col]
//   B2xt: hi plane same shape as hTt; lo plane at +LOPLANE elements.
#define ATILE_STRIDE 65536   // 4*2048*8 elements per 32-k tile of A
#define BTILE_STRIDE 32768   // 4*1024*8 elements per 32-k tile of B
#define LOPLANE 2097152      // elements per x plane (64*4*1024*8)

typedef __attribute__((ext_vector_type(8))) _Float16 f16x8;
typedef __attribute__((ext_vector_type(16))) float f32x16;

// ---------------------------------------------------------------------------
// Kernel 1: A = softmax(relu(E1 @ E2^T)) -> A2t tiled fp16
// ---------------------------------------------------------------------------
__global__ __launch_bounds__(256) void adj_softmax(const float* __restrict__ E1,
                                                   const float* __restrict__ E2,
                                                   _Float16* __restrict__ A2) {
    const int i = blockIdx.x;
    __shared__ float red[256];
    float e1[EMB];
#pragma unroll
    for (int k = 0; k < EMB; ++k) e1[k] = E1[i * EMB + k];

    float s[8];
    float mx = -1e30f;
#pragma unroll
    for (int q = 0; q < 8; ++q) {
        const int j = q * 256 + threadIdx.x;
        float d = 0.f;
#pragma unroll
        for (int k = 0; k < EMB; ++k) d += e1[k] * E2[j * EMB + k];
        d = fmaxf(d, 0.0f);
        s[q] = d;
        mx = fmaxf(mx, d);
    }
    red[threadIdx.x] = mx;
    __syncthreads();
    for (int off = 128; off > 0; off >>= 1) {
        if (threadIdx.x < off) red[threadIdx.x] = fmaxf(red[threadIdx.x], red[threadIdx.x + off]);
        __syncthreads();
    }
    mx = red[0];
    __syncthreads();

    float sum = 0.f;
#pragma unroll
    for (int q = 0; q < 8; ++q) { s[q] = expf(s[q] - mx); sum += s[q]; }
    red[threadIdx.x] = sum;
    __syncthreads();
    for (int off = 128; off > 0; off >>= 1) {
        if (threadIdx.x < off) red[threadIdx.x] += red[threadIdx.x + off];
        __syncthreads();
    }
    const float inv = 1.0f / red[0];
#pragma unroll
    for (int q = 0; q < 8; ++q) {
        const int j  = q * 256 + threadIdx.x;      // k-index of A row i
        const int tt = j >> 5, ko = (j >> 3) & 3, e = j & 7;
        A2[((size_t)(tt * 4 + ko) * 2048 + i) * 8 + e] = (_Float16)(s[q] * inv);
    }
}

// ---------------------------------------------------------------------------
// Kernel 2: x -> B2xt tiled hi/lo fp16 planes (col = (b*T+t)*C + c).
// ---------------------------------------------------------------------------
__global__ __launch_bounds__(256) void transpose_x(const float* __restrict__ x,
                                                   _Float16* __restrict__ B2x) {
    const int idx = blockIdx.x * 256 + threadIdx.x;
    const int col = idx >> 11;
    const int j   = idx & (NN - 1);               // node index (gemm K dim)
    const int bt  = col >> 1;
    const int c   = col & 1;
    const float v = x[((size_t)bt * NN + j) * CIN + c];
    const _Float16 hi = (_Float16)v;
    const _Float16 lo = (_Float16)(v - (float)hi);
    const int tt = j >> 5, ko = (j >> 3) & 3, e = j & 7;
    const size_t base = ((size_t)(tt * 4 + ko) * 1024 + col) * 8 + e;
    B2x[base] = hi; B2x[base + LOPLANE] = lo;
}

// ---------------------------------------------------------------------------
// Kernel 3: fused full-K fp16 MFMA GEMM (32x32x16) + optional gate epilogue.
// Tile M=32 nodes x N=128 cols, K=2048. Grid 512, 2 blocks/CU, 4 waves.
// Pipeline: 4-deep register ring (tiles i..i+3 in flight) + 4 LDS buffers,
// so each tile's global loads are issued ~4 phases before their ds_write —
// covers HBM latency with counted vmcnt (compiler, via reg deps).
// Two independent acc chains (k-even/k-odd subtiles) break the MFMA
// dependency chain; summed in the epilogue.
// XCD swizzle: physical XCD x owns 16 mb x 4 nb -> per-XCD L2 set =
// 2MB A-slab + 2MB hT-col-slab (fits 4MB L2).
// GATE=0: store C directly (AX path; NPROD=2 sums hi+lo planes into acc).
// GATE=1: epilogue computes gates = C*Whr + AX*Wxr + b, LSTM cell update,
//         writes c, tiled hT (ping-pong buffer), h32 on last step.
// ---------------------------------------------------------------------------
template <int NPROD, int GATE>
__global__ __launch_bounds__(256, 2) void gemm_fused(const _Float16* __restrict__ A2,
                                                     const _Float16* __restrict__ B2,
                                                     float* __restrict__ Cout,
                                                     const float* __restrict__ AX,
                                                     const float* __restrict__ Whr,
                                                     const float* __restrict__ Wxr,
                                                     const float* __restrict__ bfold,
                                                     float* __restrict__ cst,
                                                     float* __restrict__ h32,
                                                     _Float16* __restrict__ hTout,
                                                     int t, int last) {
    constexpr int BUF = 2048 + NPROD * 8192;       // A 2KB + B planes
    constexpr int STAGE = 4 * BUF;                 // 4 LDS buffers
    constexpr int SMEMSZ = GATE ? (STAGE + 16384 + 1024 + 512 + 1024) : STAGE;
    __shared__ __align__(16) char smem[SMEMSZ];

    const int tid  = threadIdx.x;
    const int w    = tid >> 6;
    const int lane = tid & 63;

    // XCD-aware decomposition: physical XCD = wg & 7 (round-robin dispatch).
    // XCD owns 16 consecutive mb x 4 consecutive nb.
    const int wg = blockIdx.x;
    const int x8 = wg & 7;
    const int s  = wg >> 3;                 // 0..63 slot within XCD
    const int mb = (x8 >> 1) * 16 + (s & 15);
    const int nb = (x8 & 1) * 4 + (s >> 4);
    const int m0 = mb * 32;
    const int n0 = nb * 128;

    float* whr_s = nullptr; float* wxr_s = nullptr; float* bfl_s = nullptr; float* axs = nullptr;
    if constexpr (GATE) {
        whr_s = (float*)(smem + STAGE);
        wxr_s = whr_s + 4096;
        bfl_s = wxr_s + 256;
        axs   = bfl_s + 128;           // [bi 4][which 2][nl 32]
        const int b0c = nb * 4;
#pragma unroll
        for (int r = 0; r < 4; ++r)
            *(float4*)&whr_s[tid * 4 + r * 1024] = *(const float4*)&Whr[tid * 4 + r * 1024];
        if (tid < 64) *(float4*)&wxr_s[tid * 4] = *(const float4*)&Wxr[tid * 4];
        if (tid < 32) *(float4*)&bfl_s[tid * 4] = *(const float4*)&bfold[tid * 4];
        axs[tid] = AX[(size_t)(m0 + (tid & 31)) * XCOLS +
                      ((b0c + (tid >> 6)) * TT + t) * CIN + ((tid >> 5) & 1)];
    }

    // ---- staging: A 128 chunks (tid<128), B 512 chunks (tid, tid+256).
    // Global tiled layout == LDS layout -> LDS offset = chunk*16 bytes.
    const int cidA = tid & 127;
    const _Float16* gpa0 = A2 + ((size_t)((cidA >> 5)) * 2048 + m0 + (cidA & 31)) * 8;
    const int lda0 = cidA * 16;
    const _Float16* gpb0 = B2 + ((size_t)(tid >> 7) * 1024 + n0 + (tid & 127)) * 8;
    const int ldb0 = 2048 + tid * 16;
    const _Float16* gpb1 = B2 + ((size_t)((tid + 256) >> 7) * 1024 + n0 + ((tid + 256) & 127)) * 8;
    const int ldb1 = 2048 + (tid + 256) * 16;
    const _Float16 *gpc0 = nullptr, *gpc1 = nullptr;
    int ldc0 = 0, ldc1 = 0;
    if constexpr (NPROD == 2) {
        gpc0 = gpb0 + LOPLANE; ldc0 = ldb0 + 8192;
        gpc1 = gpb1 + LOPLANE; ldc1 = ldb1 + 8192;
    }

    // ---- fragment offsets: lane lrow = lane&31, lg = lane>>5; wave cols w*32
    const int lrow = lane & 31, lg = lane >> 5;
    const int wc = w * 32;
    const int aoff0 = lg * 512 + lrow * 16;               // ks=0 (ko = lg)
    const int aoff1 = 1024 + lg * 512 + lrow * 16;        // ks=1 (ko = 2+lg)
    const int boff0 = 2048 + lg * 2048 + (wc + lrow) * 16;
    const int boff1 = 2048 + 4096 + lg * 2048 + (wc + lrow) * 16;

    f32x16 acc0 = (f32x16)(0.0f), acc1 = (f32x16)(0.0f);

    uint4 Ra0, Rb0, Rb1, Rc0, Rc1;     // ring set 0
    uint4 Sa0, Sb0, Sb1, Sc0, Sc1;     // ring set 1
    uint4 Ta0, Tb0, Tb1, Tc0, Tc1;     // ring set 2
    uint4 Ua0, Ub0, Ub1, Uc0, Uc1;     // ring set 3

#define LOADSET(P)                                                             \
    if (tid < 128) { P##a0 = *(const uint4*)gpa0; }                            \
    gpa0 += ATILE_STRIDE;                                                      \
    P##b0 = *(const uint4*)gpb0; gpb0 += BTILE_STRIDE;                         \
    P##b1 = *(const uint4*)gpb1; gpb1 += BTILE_STRIDE;                         \
    if constexpr (NPROD == 2) {                                                \
        P##c0 = *(const uint4*)gpc0; gpc0 += BTILE_STRIDE;                     \
        P##c1 = *(const uint4*)gpc1; gpc1 += BTILE_STRIDE;                     \
    }

#define STORESET(P, SB)                                                        \
    if (tid < 128) { *(uint4*)((SB) + lda0) = P##a0; }                         \
    *(uint4*)((SB) + ldb0) = P##b0;                                            \
    *(uint4*)((SB) + ldb1) = P##b1;                                            \
    if constexpr (NPROD == 2) {                                                \
        *(uint4*)((SB) + ldc0) = P##c0;                                        \
        *(uint4*)((SB) + ldc1) = P##c1;                                        \
    }

#define COMPUTE(BUFI) do {                                                     \
    const char* sb = smem + (BUFI) * BUF;                                      \
    f16x8 fa0 = *(const f16x8*)(sb + aoff0);                                   \
    f16x8 fa1 = *(const f16x8*)(sb + aoff1);                                   \
    f16x8 fb0 = *(const f16x8*)(sb + boff0);                                   \
    f16x8 fb1 = *(const f16x8*)(sb + boff1);                                   \
    acc0 = __builtin_amdgcn_mfma_f32_32x32x16_f16(fa0, fb0, acc0, 0, 0, 0);    \
    acc1 = __builtin_amdgcn_mfma_f32_32x32x16_f16(fa1, fb1, acc1, 0, 0, 0);    \
    if constexpr (NPROD == 2) {                                                \
        f16x8 fc0 = *(const f16x8*)(sb + boff0 + 8192);                        \
        f16x8 fc1 = *(const f16x8*)(sb + boff1 + 8192);                        \
        acc0 = __builtin_amdgcn_mfma_f32_32x32x16_f16(fa0, fc0, acc0, 0, 0, 0);\
        acc1 = __builtin_amdgcn_mfma_f32_32x32x16_f16(fa1, fc1, acc1, 0, 0, 0);\
    }                                                                          \
} while (0)

    LOADSET(R)     // tile 0
    LOADSET(S)     // tile 1
    LOADSET(T)     // tile 2
    LOADSET(U)     // tile 3
#pragma unroll 1
    for (int it = 0; it < NT2; it += 4) {
        STORESET(R, smem + 0 * BUF)            // vmcnt-waits on R only
        __syncthreads();
        LOADSET(R)                             // tile it+4 (tail over-read in-ws)
        COMPUTE(0);
        STORESET(S, smem + 1 * BUF)
        __syncthreads();
        LOADSET(S)                             // tile it+5
        COMPUTE(1);
        STORESET(T, smem + 2 * BUF)
        __syncthreads();
        LOADSET(T)                             // tile it+6
        COMPUTE(2);
        STORESET(U, smem + 3 * BUF)
        __syncthreads();
        LOADSET(U)                             // tile it+7
        COMPUTE(3);
    }
#undef LOADSET
#undef STORESET
#undef COMPUTE

    // ---- C layout per 32x32 acc: col=lane&31, row=(r&3)+8*(r>>2)+4*lg ----
    if constexpr (!GATE) {
        const int colg = n0 + wc + lrow;
#pragma unroll
        for (int r = 0; r < 16; ++r) {
            const int rp = (r & 3) + 8 * (r >> 2) + 4 * lg;
            Cout[(size_t)(m0 + rp) * XCOLS + colg] = acc0[r] + acc1[r];
        }
    } else {
        // stage Ah tile to LDS (overlays staging buffers)
        __syncthreads();
        float* ah = (float*)smem;               // [32][129]
#pragma unroll
        for (int r = 0; r < 16; ++r) {
            const int rp = (r & 3) + 8 * (r >> 2) + 4 * lg;
            ah[rp * 129 + wc + lrow] = acc0[r] + acc1[r];
        }
        __syncthreads();

        const int nl2 = tid & 31;               // node within tile
        const int hq  = tid >> 5;               // 0..7 -> h = hq*4+u
        const int b0c = nb * 4;
        const int nd  = m0 + nl2;
        const size_t ntbase = ((size_t)((nd >> 5) * 4 + ((nd >> 3) & 3)) * 1024) * 8 + (nd & 7);

#pragma unroll 1
        for (int bi = 0; bi < 4; ++bi) {
            const float ax0 = axs[bi * 64 + nl2];
            const float ax1 = axs[bi * 64 + 32 + nl2];
            float ar[32];
#pragma unroll
            for (int k = 0; k < 32; ++k) ar[k] = ah[nl2 * 129 + bi * 32 + k];

            float a4[4][4];
#pragma unroll
            for (int u = 0; u < 4; ++u) {
                const int h = hq * 4 + u;
#pragma unroll
                for (int g = 0; g < 4; ++g)
                    a4[u][g] = bfl_s[h * 4 + g] + ax0 * wxr_s[h * 4 + g] + ax1 * wxr_s[128 + h * 4 + g];
            }
#pragma unroll 4
            for (int k = 0; k < 32; ++k) {
                const float av = ar[k];
#pragma unroll
                for (int u = 0; u < 4; ++u) {
                    const float* wp = &whr_s[(k * 32 + hq * 4 + u) * 4];
                    a4[u][0] += av * wp[0];
                    a4[u][1] += av * wp[1];
                    a4[u][2] += av * wp[2];
                    a4[u][3] += av * wp[3];
                }
            }

            const int b = b0c + bi;
            const size_t off = (size_t)nd * HCOLS + b * HH + hq * 4;
            const float4 co = *(const float4*)(cst + off);
            const float cold[4] = {co.x, co.y, co.z, co.w};
            float cn[4], hn[4];
#pragma unroll
            for (int u = 0; u < 4; ++u) {
                const float i_ = 1.0f / (1.0f + expf(-a4[u][0]));
                const float f_ = 1.0f / (1.0f + expf(-a4[u][1]));
                const float o_ = 1.0f / (1.0f + expf(-a4[u][2]));
                const float g_ = tanhf(a4[u][3]);
                const float ct = f_ * cold[u] + i_ * g_;
                cn[u] = ct;
                hn[u] = o_ * tanhf(ct);
            }
            *(float4*)(cst + off) = make_float4(cn[0], cn[1], cn[2], cn[3]);
            if (last) *(float4*)(h32 + off) = make_float4(hn[0], hn[1], hn[2], hn[3]);
#pragma unroll
            for (int u = 0; u < 4; ++u)
                hTout[ntbase + (size_t)(b * HH + hq * 4 + u) * 8] = (_Float16)hn[u];
        }
    }
}

// ---------------------------------------------------------------------------
// Kernel 3c: weight prep. Whr[k][h][g] = Wh[k][g*32+h]; Wxr[c][h][g]; bfold.
// ---------------------------------------------------------------------------
__global__ __launch_bounds__(256) void prep_weights(const float* __restrict__ Wx,
                                                    const float* __restrict__ bx,
                                                    const float* __restrict__ Wh,
                                                    const float* __restrict__ bh,
                                                    float* __restrict__ Whr,
                                                    float* __restrict__ Wxr,
                                                    float* __restrict__ bfold) {
    const int tid = threadIdx.x;
#pragma unroll
    for (int r = 0; r < 16; ++r) {
        const int idx = tid * 16 + r;           // 4096
        const int k = idx >> 7, rem = idx & 127;
        const int h = rem >> 2, g = rem & 3;
        Whr[idx] = Wh[k * GC + g * HH + h];
    }
    {
        const int idx = tid;                    // 256
        const int c = idx >> 7, rem = idx & 127;
        const int h = rem >> 2, g = rem & 3;
        Wxr[idx] = Wx[c * GC + g * HH + h];
    }
    if (tid < 128) {
        const int h = tid >> 2, g = tid & 3;
        bfold[tid] = bx[g * HH + h] + bh[g * HH + h];
    }
}

// ---------------------------------------------------------------------------
// Kernel 4: t=0 gate update only (no recurrent term), 64 nodes x 4 batches.
// ---------------------------------------------------------------------------
__global__ __launch_bounds__(256) void gate_update(const float* __restrict__ AX,
                                                   const float* __restrict__ Whr,
                                                   const float* __restrict__ Wxr,
                                                   const float* __restrict__ bfold,
                                                   float* __restrict__ c,
                                                   float* __restrict__ h32,
                                                   _Float16* __restrict__ hT) {
    const int n0 = blockIdx.x * 64;
    const int b0 = blockIdx.y * 4;
    const int tid = threadIdx.x;
    __shared__ float wxr[256];
    __shared__ float bfl[128];
    __shared__ float axs[2][64];

    if (tid < 64)  *(float4*)&wxr[tid * 4] = *(const float4*)&Wxr[tid * 4];
    if (tid < 32)  *(float4*)&bfl[tid * 4] = *(const float4*)&bfold[tid * 4];

    const int nl = tid & 63;
    const int hq = tid >> 6;

    const int nd = n0 + nl;
    const size_t ntbase = ((size_t)((nd >> 5) * 4 + ((nd >> 3) & 3)) * 1024) * 8 + (nd & 7);

#pragma unroll 1
    for (int bi = 0; bi < 4; ++bi) {
        const int b = b0 + bi;
        if (bi) __syncthreads();
        if (tid < 128) {
            const int which = tid >> 6, nls = tid & 63;
            axs[which][nls] = AX[(size_t)(n0 + nls) * XCOLS + (b * TT + 0) * CIN + which];
        }
        __syncthreads();

        const float ax0 = axs[0][nl], ax1 = axs[1][nl];
        float cn[8], hn[8];
#pragma unroll
        for (int u = 0; u < 8; ++u) {
            const int h = hq * 8 + u;
            float a0 = bfl[h * 4 + 0] + ax0 * wxr[h * 4 + 0] + ax1 * wxr[128 + h * 4 + 0];
            float a1 = bfl[h * 4 + 1] + ax0 * wxr[h * 4 + 1] + ax1 * wxr[128 + h * 4 + 1];
            float a2 = bfl[h * 4 + 2] + ax0 * wxr[h * 4 + 2] + ax1 * wxr[128 + h * 4 + 2];
            float a3 = bfl[h * 4 + 3] + ax0 * wxr[h * 4 + 3] + ax1 * wxr[128 + h * 4 + 3];
            const float i_ = 1.0f / (1.0f + expf(-a0));
            const float f_ = 1.0f / (1.0f + expf(-a1));
            const float o_ = 1.0f / (1.0f + expf(-a2));
            const float g_ = tanhf(a3);
            const float ct = i_ * g_;          // c_old = 0
            (void)f_;
            cn[u] = ct;
            hn[u] = o_ * tanhf(ct);
        }
        const size_t off = (size_t)nd * HCOLS + b * HH + hq * 8;
        *(float4*)(c + off)       = make_float4(cn[0], cn[1], cn[2], cn[3]);
        *(float4*)(c + off + 4)   = make_float4(cn[4], cn[5], cn[6], cn[7]);
        *(float4*)(h32 + off)     = make_float4(hn[0], hn[1], hn[2], hn[3]);
        *(float4*)(h32 + off + 4) = make_float4(hn[4], hn[5], hn[6], hn[7]);
#pragma unroll
        for (int u = 0; u < 8; ++u)
            hT[ntbase + (size_t)(b * HH + hq * 8 + u) * 8] = (_Float16)hn[u];
    }
}

// ---------------------------------------------------------------------------
// Kernel 5: out[b][th][n] = bp[th] + sum_k h[n][b*H+k] * Wp[k][th]
// ---------------------------------------------------------------------------
__global__ __launch_bounds__(256) void head_kernel(const float* __restrict__ h,
                                                   const float* __restrict__ Wp,
                                                   const float* __restrict__ bp,
                                                   float* __restrict__ out) {
    const int idx = blockIdx.x * 256 + threadIdx.x;
    const int b = idx >> 11;
    const int n = idx & (NN - 1);
    float hv[HH];
    const float* hp = h + (size_t)n * HCOLS + b * HH;
#pragma unroll
    for (int k = 0; k < HH; ++k) hv[k] = hp[k];
#pragma unroll
    for (int th = 0; th < HOR; ++th) {
        float acc = bp[th];
#pragma unroll
        for (int k = 0; k < HH; ++k) acc += hv[k] * Wp[k * HOR + th];
        out[((size_t)b * HOR + th) * NN + n] = acc;
    }
}

// ---------------------------------------------------------------------------
extern "C" void kernel_launch(void* const* d_in, const int* in_sizes, int n_in,
                              void* d_out, int out_size, void* d_ws, size_t ws_size,
                              hipStream_t stream) {
    const float* x  = (const float*)d_in[0];
    const float* E1 = (const float*)d_in[1];
    const float* E2 = (const float*)d_in[2];
    const float* Wx = (const float*)d_in[3];
    const float* bx = (const float*)d_in[4];
    const float* Wh = (const float*)d_in[5];
    const float* bh = (const float*)d_in[6];
    const float* Wp = (const float*)d_in[7];
    const float* bp = (const float*)d_in[8];

    char* ws = (char*)d_ws;
    _Float16* A2  = (_Float16*)(ws);                    //  8 MB  tiled A
    _Float16* B2x = (_Float16*)(ws + ( 8ull << 20));    //  8 MB  tiled x hi/lo
    _Float16* hT0 = (_Float16*)(ws + (16ull << 20));    //  4 MB  tiled h (ping)
    _Float16* hT1 = (_Float16*)(ws + (20ull << 20));    //  4 MB  tiled h (pong)
    float* AX   = (float*)(ws + (24ull << 20));         //  8 MB
    float* cst  = (float*)(ws + (32ull << 20));         //  8 MB
    float* h32  = (float*)(ws + (40ull << 20));         //  8 MB
    float* Whr  = (float*)(ws + (48ull << 20));         // 16 KB
    float* Wxr  = (float*)(ws + (48ull << 20) + 65536);
    float* bfold= (float*)(ws + (48ull << 20) + 131072);
    _Float16* hTb[2] = {hT0, hT1};

    adj_softmax<<<NN, 256, 0, stream>>>(E1, E2, A2);
    transpose_x<<<(XCOLS * NN) / 256, 256, 0, stream>>>(x, B2x);
    prep_weights<<<1, 256, 0, stream>>>(Wx, bx, Wh, bh, Whr, Wxr, bfold);

    // x path: AX = A*Xhi + A*Xlo, written directly (no partials)
    gemm_fused<2, 0><<<512, 256, 0, stream>>>(A2, B2x, AX, nullptr, nullptr, nullptr,
                                              nullptr, nullptr, nullptr, nullptr, 0, 0);

    // t = 0: gates from AX only
    gate_update<<<dim3(NN / 64, BB / 4), 256, 0, stream>>>(AX, Whr, Wxr, bfold,
                                                           cst, h32, hTb[0]);
    // t = 1..15: fused GEMM + gate epilogue; hT ping-pong (read prev, write cur)
    for (int t = 1; t < TT; ++t) {
        gemm_fused<1, 1><<<512, 256, 0, stream>>>(A2, hTb[(t + 1) & 1], nullptr, AX,
                                                  Whr, Wxr, bfold, cst, h32,
                                                  hTb[t & 1], t, t == TT - 1 ? 1 : 0);
    }

    head_kernel<<<(BB * NN) / 256, 256, 0, stream>>>(h32, Wp, bp, (float*)d_out);
}